// Round 9
// baseline (126.454 us; speedup 1.0000x reference)
//
#include <hip/hip_runtime.h>
#include <hip/hip_bf16.h>

#define LOG2PI 1.8378770664093453f

// N=16384, M(K-dim)=4096, K(latent)=64.
// GEMM: Out[n][c] = sum_m x[n][m] * Bcat[c][m], staged cols c in [0,160) (144 real):
//   c 0-63: W_enc_mu col, 64-127: W_dec_mu row (c-64), 128: W_enc_sigma, 129: b_dec_mu.
// Split-K: KSPLIT slices of m; partials Pp[row][ks][144] (stride ppstride).
// col 130 of each partial = per-slice sum(x^2); cols 131-143 zero.
//
// BM=128, BK=64, 4 waves (2m x 2n), 2 blocks/CU, 16 steps (ksplit=4).
// A LDS image (bf16): row*128 + (u ^ (row&7))*16 holds x[row][t*64 + u*8 .. +8],
//   staged global->reg(fp32)->cvt->ds_write_b64.
// Bp image per k-tile kt (64 m): 20480 B: col*128 + u*16 holds
//   Bcat[col][kt*64 + (u^(col&7))*8 .. +8] as bf16x8; staged via global_load_lds.

typedef __attribute__((ext_vector_type(8))) short bf16x8;
typedef __attribute__((ext_vector_type(4))) float f32x4;

__device__ __forceinline__ unsigned short f2bf(float f) {
    unsigned int u = __builtin_bit_cast(unsigned int, f);
    u += 0x7FFFu + ((u >> 16) & 1u);
    return (unsigned short)(u >> 16);
}
__device__ __forceinline__ void gll16(const void* g, void* l) {
    __builtin_amdgcn_global_load_lds(
        (const __attribute__((address_space(1))) void*)g,
        (__attribute__((address_space(3))) void*)l, 16, 0, 0);
}

// ---------------- pack B: 64 blocks, one per 64-m k-tile (coalesced)
__global__ __launch_bounds__(256) void pack_b_kernel(const float* __restrict__ We,
        const float* __restrict__ Wes, const float* __restrict__ Wd,
        const float* __restrict__ bd, unsigned char* __restrict__ Bp) {
    __shared__ float WeL[4096];   // [64 m][64 c]
    __shared__ float WdL[4096];   // [64 r][64 m]
    __shared__ float WesL[64], bdL[64];
    const int kt = blockIdx.x;    // [0,64)
    const int t = threadIdx.x;
#pragma unroll
    for (int i = 0; i < 4; ++i) {
        int q = t + 256 * i;
        *reinterpret_cast<f32x4*>(WeL + q * 4) =
            *reinterpret_cast<const f32x4*>(We + (size_t)kt * 4096 + q * 4);
    }
#pragma unroll
    for (int i = 0; i < 4; ++i) {
        int f = t + 256 * i;
        int r = f >> 4, s4 = f & 15;
        *reinterpret_cast<f32x4*>(WdL + r * 64 + s4 * 4) =
            *reinterpret_cast<const f32x4*>(Wd + (size_t)r * 4096 + kt * 64 + s4 * 4);
    }
    if (t < 16) {
        *reinterpret_cast<f32x4*>(WesL + t * 4) =
            *reinterpret_cast<const f32x4*>(Wes + kt * 64 + t * 4);
    } else if (t < 32) {
        int q = t - 16;
        *reinterpret_cast<f32x4*>(bdL + q * 4) =
            *reinterpret_cast<const f32x4*>(bd + kt * 64 + q * 4);
    }
    __syncthreads();
#pragma unroll
    for (int i = 0; i < 5; ++i) {
        int cidx = t + 256 * i;            // [0,1280) = col*8 + u
        int col = cidx >> 3, u = cidx & 7;
        int ku = u ^ (col & 7);
        unsigned short out[8];
#pragma unroll
        for (int j = 0; j < 8; ++j) {
            int m = ku * 8 + j;
            float v = 0.f;
            if (col < 64)        v = WeL[m * 64 + col];
            else if (col < 128)  v = WdL[(col - 64) * 64 + m];
            else if (col == 128) v = WesL[m];
            else if (col == 129) v = bdL[m];
            out[j] = f2bf(v);
        }
        *reinterpret_cast<uint4*>(Bp + ((size_t)kt * 1280 + cidx) * 16) =
            *reinterpret_cast<uint4*>(out);
    }
}

// ---------------- prep (coalesced): G pairs + h + e via row-dot blocks
__global__ __launch_bounds__(256) void prep_g_kernel(const float* __restrict__ Wd,
        const float* __restrict__ bd, float* __restrict__ G,
        float* __restrict__ hv, float* __restrict__ ev) {
    __shared__ float red[256];
    const int b = blockIdx.x, t = threadIdx.x;
    float p = 0.f;
    if (b < 4096) {
        int a = b >> 6, c = b & 63;
        const f32x4* ra = reinterpret_cast<const f32x4*>(Wd + (size_t)a * 4096);
        const f32x4* rc = reinterpret_cast<const f32x4*>(Wd + (size_t)c * 4096);
        for (int j = t; j < 1024; j += 256) {
            f32x4 u = ra[j], v = rc[j];
            p += u[0] * v[0] + u[1] * v[1] + u[2] * v[2] + u[3] * v[3];
        }
    } else if (b < 4160) {
        int a = b - 4096;
        const f32x4* ra = reinterpret_cast<const f32x4*>(Wd + (size_t)a * 4096);
        const f32x4* rb = reinterpret_cast<const f32x4*>(bd);
        for (int j = t; j < 1024; j += 256) {
            f32x4 u = ra[j], v = rb[j];
            p += u[0] * v[0] + u[1] * v[1] + u[2] * v[2] + u[3] * v[3];
        }
    } else {
        const f32x4* rb = reinterpret_cast<const f32x4*>(bd);
        for (int j = t; j < 1024; j += 256) {
            f32x4 v = rb[j];
            p += v[0] * v[0] + v[1] * v[1] + v[2] * v[2] + v[3] * v[3];
        }
    }
    red[t] = p;
    __syncthreads();
    for (int s = 128; s > 0; s >>= 1) { if (t < s) red[t] += red[t + s]; __syncthreads(); }
    if (t == 0) {
        if (b < 4096) G[b] = red[0];
        else if (b < 4160) hv[b - 4096] = red[0];
        else ev[0] = red[0];
    }
}

// ---------------- main GEMM: BM=128, BK=64, reg-staged bf16 A, 1 barrier/step
__global__ __launch_bounds__(256, 2) void gemm_kernel(const float* __restrict__ x,
        const unsigned char* __restrict__ Bp, float* __restrict__ Pp,
        int steps, int kslice, int ppstride) {
    __shared__ __align__(16) char lds[73728];    // 2 bufs x (A 16384 bf16 + B 20480)
    __shared__ float sxL[128];
    const int tid = threadIdx.x;
    const int lane = tid & 63, w = tid >> 6;
    const int wm = w >> 1, wn = w & 1;           // 2m x 2n waves, wave owns 64x80
    const int l15 = lane & 15, kg = lane >> 4;
    const int rowbase = blockIdx.x * 128;
    const int ks = blockIdx.y;

    // A global: piece i covers row i*16 + (tid>>4), 16-B unit tid&15 (coalesced:
    // 16 consecutive threads read 256 contiguous bytes of one row per step)
    const float* xA[8];
#pragma unroll
    for (int i = 0; i < 8; ++i)
        xA[i] = x + (size_t)(rowbase + i * 16 + (tid >> 4)) * 4096
                  + (size_t)ks * kslice + (tid & 15) * 4;
    const unsigned char* gB0 = Bp + (size_t)tid * 16;

    // A LDS write constants: unit u = (tid&15)>>1, slot = u ^ ((tid>>4)&7)
    const int wb_off = (((((tid & 15) >> 1) ^ ((tid >> 4) & 7))) << 4) + (tid & 1) * 8;

    f32x4 acc[4][5];
#pragma unroll
    for (int mi = 0; mi < 4; ++mi)
#pragma unroll
        for (int ni = 0; ni < 5; ++ni) acc[mi][ni] = (f32x4){0.f, 0.f, 0.f, 0.f};
    float sxp[8] = {0.f, 0.f, 0.f, 0.f, 0.f, 0.f, 0.f, 0.f};
    float4 ga[8];

#define ALOAD(tt) do { \
        _Pragma("unroll") \
        for (int i_ = 0; i_ < 8; ++i_) \
            ga[i_] = *reinterpret_cast<const float4*>(xA[i_] + (tt) * 64); \
    } while (0)

#define BSTAGE(buf, tt) do { \
        _Pragma("unroll") \
        for (int j_ = 0; j_ < 5; ++j_) \
            gll16(gB0 + (size_t)(ks * steps + (tt)) * 20480 + j_ * 4096, \
                  lds + (buf) * 36864 + 16384 + j_ * 4096 + tid * 16); \
    } while (0)

#define CVTWRITE(buf) do { \
        char* Ab = lds + (buf) * 36864; \
        _Pragma("unroll") \
        for (int i_ = 0; i_ < 8; ++i_) { \
            int row_ = i_ * 16 + (tid >> 4); \
            unsigned int lo_ = (unsigned int)f2bf(ga[i_].x) \
                             | ((unsigned int)f2bf(ga[i_].y) << 16); \
            unsigned int hi_ = (unsigned int)f2bf(ga[i_].z) \
                             | ((unsigned int)f2bf(ga[i_].w) << 16); \
            *reinterpret_cast<uint2*>(Ab + row_ * 128 + wb_off) = make_uint2(lo_, hi_); \
            sxp[i_] += ga[i_].x * ga[i_].x + ga[i_].y * ga[i_].y \
                     + ga[i_].z * ga[i_].z + ga[i_].w * ga[i_].w; \
        } \
    } while (0)

#define COMPUTE(buf) do { \
        char* A0 = lds + (buf) * 36864; \
        char* B0 = A0 + 16384; \
        _Pragma("unroll") \
        for (int kk_ = 0; kk_ < 2; ++kk_) { \
            bf16x8 bfr[5]; \
            _Pragma("unroll") \
            for (int ni_ = 0; ni_ < 5; ++ni_) { \
                int col_ = wn * 80 + ni_ * 16 + l15; \
                bfr[ni_] = *reinterpret_cast<const bf16x8*>( \
                    B0 + col_ * 128 + (((kk_ * 4 + kg) ^ (col_ & 7)) << 4)); \
            } \
            _Pragma("unroll") \
            for (int mi_ = 0; mi_ < 4; ++mi_) { \
                int row_ = wm * 64 + mi_ * 16 + l15; \
                bf16x8 af_ = *reinterpret_cast<const bf16x8*>( \
                    A0 + row_ * 128 + (((kk_ * 4 + kg) ^ (row_ & 7)) << 4)); \
                _Pragma("unroll") \
                for (int ni_ = 0; ni_ < 5; ++ni_) \
                    acc[mi_][ni_] = __builtin_amdgcn_mfma_f32_16x16x32_bf16( \
                        af_, bfr[ni_], acc[mi_][ni_], 0, 0, 0); \
            } \
        } \
    } while (0)

    // prologue: tile 0 into buf 0
    ALOAD(0);
    BSTAGE(0, 0);
    CVTWRITE(0);                               // compiler waits ga; writes bf16 A
    asm volatile("s_waitcnt vmcnt(0) lgkmcnt(0)" ::: "memory");
    __builtin_amdgcn_s_barrier();
    asm volatile("" ::: "memory");

    int cur = 0;
    for (int t = 0; t < steps; ++t) {
        if (t + 1 < steps) { ALOAD(t + 1); BSTAGE(cur ^ 1, t + 1); }
        COMPUTE(cur);
        if (t + 1 < steps) {
            CVTWRITE(cur ^ 1);
            asm volatile("s_waitcnt vmcnt(0) lgkmcnt(0)" ::: "memory");
            __builtin_amdgcn_s_barrier();
            asm volatile("" ::: "memory");
        }
        cur ^= 1;
    }
#undef ALOAD
#undef BSTAGE
#undef CVTWRITE
#undef COMPUTE

    // sx2 row sums: reduce the 16 unit-columns of each row (lanes l15)
#pragma unroll
    for (int i = 0; i < 8; ++i) {
        float v = sxp[i];
        v += __shfl_xor(v, 1); v += __shfl_xor(v, 2);
        v += __shfl_xor(v, 4); v += __shfl_xor(v, 8);
        if (l15 == 0) sxL[i * 16 + (tid >> 4)] = v;
    }

    // ---- coalesced writeback in two 64-row passes via LDS C-tile [64][148]
    float* C = reinterpret_cast<float*>(lds);
#pragma unroll
    for (int pass = 0; pass < 2; ++pass) {
        __syncthreads();
        if (wm == pass) {
#pragma unroll
            for (int mi = 0; mi < 4; ++mi)
#pragma unroll
                for (int ni = 0; ni < 5; ++ni) {
                    int col = wn * 80 + ni * 16 + l15;
                    if (col < 148 && col != 130) {
#pragma unroll
                        for (int i2 = 0; i2 < 4; ++i2)
                            C[(mi * 16 + kg * 4 + i2) * 148 + col] = acc[mi][ni][i2];
                    }
                }
        }
        if (tid < 64) C[tid * 148 + 130] = sxL[pass * 64 + tid];
        __syncthreads();
#pragma unroll
        for (int i = 0; i < 9; ++i) {
            int idx = tid + 256 * i;
            int r = idx / 36, c4 = idx % 36;
            f32x4 v = *reinterpret_cast<const f32x4*>(C + r * 148 + c4 * 4);
            *reinterpret_cast<f32x4*>(
                Pp + (size_t)(rowbase + pass * 64 + r) * ppstride + ks * 144 + c4 * 4) = v;
        }
    }
}

// ---------------- phase 2: plain [64][64] G, XOR-permuted conflict-free matvec
__global__ __launch_bounds__(256) void phase2_kernel(const float* __restrict__ Pp,
        const float* __restrict__ noise, const float* __restrict__ bem,
        const float* __restrict__ Wds, const float* __restrict__ bes_p,
        const float* __restrict__ bds_p, const float* __restrict__ G,
        const float* __restrict__ hv, const float* __restrict__ ev,
        float* __restrict__ partial, int ksplit, int ppstride) {
    __shared__ float Gl[4096];
    __shared__ float hl[64], wl[64], beml[64];
    __shared__ float zs[4][64];
    __shared__ float red[4];
    int tid = threadIdx.x;
    for (int i = tid; i < 4096; i += 256) Gl[i] = G[i];
    if (tid < 64) { hl[tid] = hv[tid]; wl[tid] = Wds[tid]; beml[tid] = bem[tid]; }
    __syncthreads();
    float bes = bes_p[0], bds = bds_p[0], e = ev[0];
    int wid = tid >> 6, k = tid & 63;
    const int sw = (k & 15) << 2;
    float wacc = 0.f;
#pragma unroll
    for (int rr = 0; rr < 8; ++rr) {
        int row = blockIdx.x * 32 + wid * 8 + rr;
        const float* base = Pp + (size_t)row * ppstride;
        float zmu = beml[k], ck = 0.f, se = bes, dd = 0.f, sx2 = 0.f;
        for (int s = 0; s < ksplit; ++s) {
            const float* b2 = base + s * 144;
            zmu += b2[k]; ck += b2[64 + k];
            se += b2[128]; dd += b2[129]; sx2 += b2[130];
        }
        float nz = noise[(size_t)row * 64 + k];
        float s2 = se * se;
        float z = fmaf(s2, nz, zmu);
        zs[wid][k] = z;
        float t0 = 0.f, t1 = 0.f, t2 = 0.f, t3 = 0.f;
        const float* gr = &Gl[k * 64];
        const float* zr = &zs[wid][0];
#pragma unroll
        for (int jb = 0; jb < 16; ++jb) {
            int p = (jb * 4) ^ sw;
            f32x4 gv = *reinterpret_cast<const f32x4*>(gr + p);
            f32x4 zv = *reinterpret_cast<const f32x4*>(zr + p);
            t0 = fmaf(gv[0], zv[0], t0); t1 = fmaf(gv[1], zv[1], t1);
            t2 = fmaf(gv[2], zv[2], t2); t3 = fmaf(gv[3], zv[3], t3);
        }
        float t = (t0 + t1) + (t2 + t3);
        float ra = z * z;
        float rb = nz * nz;
        float rc = z * wl[k];
        float rd = z * ck;
        float re = z * fmaf(2.f, hl[k], t);
#pragma unroll
        for (int d = 1; d < 64; d <<= 1) {
            ra += __shfl_xor(ra, d); rb += __shfl_xor(rb, d);
            rc += __shfl_xor(rc, d); rd += __shfl_xor(rd, d);
            re += __shfl_xor(re, d);
        }
        float sdec = rc + bds;
        float xxmu = rd + dd;
        float xmu2 = re + e;
        float sq_lik = sx2 - 2.f * xxmu + xmu2;
        float vz = s2 * s2;
        float sd2 = sdec * sdec;
        float vx = sd2 * sd2;
        wacc += 0.5f * (4096.f * LOG2PI + 4096.f * __logf(vx) + sq_lik / vx
                        + ra - 64.f * __logf(vz) - rb);
    }
    if (k == 0) red[wid] = wacc;
    __syncthreads();
    if (tid == 0) partial[blockIdx.x] = red[0] + red[1] + red[2] + red[3];
}

__global__ __launch_bounds__(256) void final_reduce_kernel(const float* __restrict__ partial,
                                                           float* __restrict__ out) {
    __shared__ float red[4];
    int tid = threadIdx.x;
    float v = 0.f;
    for (int i = tid; i < 512; i += 256) v += partial[i];
#pragma unroll
    for (int d = 1; d < 64; d <<= 1) v += __shfl_xor(v, d);
    if ((tid & 63) == 0) red[tid >> 6] = v;
    __syncthreads();
    if (tid == 0) out[0] = red[0] + red[1] + red[2] + red[3];
}

extern "C" void kernel_launch(void* const* d_in, const int* in_sizes, int n_in,
                              void* d_out, int out_size, void* d_ws, size_t ws_size,
                              hipStream_t stream) {
    const float* x     = (const float*)d_in[0];
    const float* noise = (const float*)d_in[1];
    const float* We    = (const float*)d_in[2];
    const float* bem   = (const float*)d_in[3];
    const float* Wes   = (const float*)d_in[4];
    const float* bes   = (const float*)d_in[5];
    const float* Wd    = (const float*)d_in[6];
    const float* bdm   = (const float*)d_in[7];
    const float* Wds   = (const float*)d_in[8];
    const float* bds   = (const float*)d_in[9];

    int ksplit = (ws_size >= 39340544ull) ? 4 : (ws_size >= 20466176ull ? 2 : 1);
    int steps = 64 / ksplit;          // BK=64 tiles per k-slice
    int kslice = steps * 64;
    int ppstride = ksplit * 144;

    char* ws = (char*)d_ws;
    size_t ppbytes = (size_t)16384 * ppstride * 4;
    float* Pp           = (float*)ws;
    unsigned char* Bp   = (unsigned char*)(ws + ppbytes);   // 1,310,720 B used
    float* G            = (float*)(ws + ppbytes + 1572864);
    float* hv           = (float*)(ws + ppbytes + 1572864 + 16384);
    float* ev           = (float*)(ws + ppbytes + 1572864 + 16640);
    float* partial      = (float*)(ws + ppbytes + 1572864 + 16896);

    pack_b_kernel<<<64, 256, 0, stream>>>(We, Wes, Wd, bdm, Bp);
    prep_g_kernel<<<4161, 256, 0, stream>>>(Wd, bdm, G, hv, ev);
    gemm_kernel<<<dim3(128, ksplit), 256, 0, stream>>>(x, Bp, Pp, steps, kslice, ppstride);
    phase2_kernel<<<512, 256, 0, stream>>>(Pp, noise, bem, Wds, bes, bds, G, hv, ev,
                                           partial, ksplit, ppstride);
    final_reduce_kernel<<<1, 256, 0, stream>>>(partial, (float*)d_out);
}

// Round 10
// 114.195 us; speedup vs baseline: 1.1073x; 1.1073x over previous
//
#include <hip/hip_runtime.h>
#include <hip/hip_bf16.h>

#define LOG2PI 1.8378770664093453f

// N=16384, M(K-dim)=4096, K(latent)=64.
// GEMM: Out[n][c] = sum_m x[n][m] * Bcat[c][m], staged cols c in [0,144):
//   c 0-63: W_enc_mu col, 64-127: W_dec_mu row (c-64), 128: W_enc_sigma, 129: b_dec_mu.
// Split-K: KSPLIT slices of m; partials Pp[row][ks][144] (stride ppstride).
// col 130 of each partial = per-slice sum(x^2); cols 131-143 zero.
//
// Bp layout: per k-tile kt (32 m-values, 128 tiles), a 9216-B linear LDS image:
//   offset col*64 + u*16 holds Bcat[col][kt*32 + (u^q(col))*8 .. +8] as 8 bf16,
//   q(col) = (col + (col>>2)) & 3  (2-way-free ds_read banking). 144 cols.
// A LDS image per step: row*128 + u8*16 holds x[row][t*32 + (u8^(row&7))*4 ..+4] fp32.
// BM=128, BK=32, 4 waves (2m x 2n asym: 5/4 frags), 3 blocks/CU.

typedef __attribute__((ext_vector_type(8))) short bf16x8;
typedef __attribute__((ext_vector_type(4))) float f32x4;

__device__ __forceinline__ unsigned short f2bf(float f) {
    unsigned int u = __builtin_bit_cast(unsigned int, f);
    u += 0x7FFFu + ((u >> 16) & 1u);
    return (unsigned short)(u >> 16);
}
__device__ __forceinline__ short f2bf_s(float f) {
    return (short)__builtin_bit_cast(unsigned short, __float2bfloat16(f));
}
__device__ __forceinline__ void gll16(const void* g, void* l) {
    __builtin_amdgcn_global_load_lds(
        (const __attribute__((address_space(1))) void*)g,
        (__attribute__((address_space(3))) void*)l, 16, 0, 0);
}

// ---------------- pack B (coalesced): one block per k-tile of 32 m-values
__global__ __launch_bounds__(256) void pack_b_kernel(const float* __restrict__ We,
        const float* __restrict__ Wes, const float* __restrict__ Wd,
        const float* __restrict__ bd, unsigned char* __restrict__ Bp) {
    __shared__ float WeL[2048];   // [32 m][64 c]
    __shared__ float WdL[2048];   // [64 r][32 m]
    __shared__ float WesL[32], bdL[32];
    const int kt = blockIdx.x;    // [0,128)
    const int t = threadIdx.x;
#pragma unroll
    for (int i = 0; i < 2; ++i) {
        int q = t + 256 * i;
        *reinterpret_cast<f32x4*>(WeL + q * 4) =
            *reinterpret_cast<const f32x4*>(We + (size_t)kt * 2048 + q * 4);
    }
#pragma unroll
    for (int i = 0; i < 2; ++i) {
        int f = t + 256 * i;
        int r = f >> 3, s4 = f & 7;
        *reinterpret_cast<f32x4*>(WdL + r * 32 + s4 * 4) =
            *reinterpret_cast<const f32x4*>(Wd + (size_t)r * 4096 + kt * 32 + s4 * 4);
    }
    if (t < 8) {
        *reinterpret_cast<f32x4*>(WesL + t * 4) =
            *reinterpret_cast<const f32x4*>(Wes + kt * 32 + t * 4);
    } else if (t < 16) {
        int q = t - 8;
        *reinterpret_cast<f32x4*>(bdL + q * 4) =
            *reinterpret_cast<const f32x4*>(bd + kt * 32 + q * 4);
    }
    __syncthreads();
#pragma unroll
    for (int i = 0; i < 3; ++i) {
        int cidx = t + 256 * i;            // [0,576) = col*4 + u
        if (cidx < 576) {
            int col = cidx >> 2, u = cidx & 3;
            int ku = u ^ ((col + (col >> 2)) & 3);
            unsigned short out[8];
#pragma unroll
            for (int j = 0; j < 8; ++j) {
                int ml = ku * 8 + j;
                float v = 0.f;
                if (col < 64)        v = WeL[ml * 64 + col];
                else if (col < 128)  v = WdL[(col - 64) * 32 + ml];
                else if (col == 128) v = WesL[ml];
                else if (col == 129) v = bdL[ml];
                out[j] = f2bf(v);
            }
            *reinterpret_cast<uint4*>(Bp + ((size_t)kt * 576 + cidx) * 16) =
                *reinterpret_cast<uint4*>(out);
        }
    }
}

// ---------------- prep (coalesced): G pairs + h + e via row-dot blocks
__global__ __launch_bounds__(256) void prep_g_kernel(const float* __restrict__ Wd,
        const float* __restrict__ bd, float* __restrict__ G,
        float* __restrict__ hv, float* __restrict__ ev) {
    __shared__ float red[256];
    const int b = blockIdx.x, t = threadIdx.x;
    float p = 0.f;
    if (b < 4096) {
        int a = b >> 6, c = b & 63;
        const f32x4* ra = reinterpret_cast<const f32x4*>(Wd + (size_t)a * 4096);
        const f32x4* rc = reinterpret_cast<const f32x4*>(Wd + (size_t)c * 4096);
        for (int j = t; j < 1024; j += 256) {
            f32x4 u = ra[j], v = rc[j];
            p += u[0] * v[0] + u[1] * v[1] + u[2] * v[2] + u[3] * v[3];
        }
    } else if (b < 4160) {
        int a = b - 4096;
        const f32x4* ra = reinterpret_cast<const f32x4*>(Wd + (size_t)a * 4096);
        const f32x4* rb = reinterpret_cast<const f32x4*>(bd);
        for (int j = t; j < 1024; j += 256) {
            f32x4 u = ra[j], v = rb[j];
            p += u[0] * v[0] + u[1] * v[1] + u[2] * v[2] + u[3] * v[3];
        }
    } else {
        const f32x4* rb = reinterpret_cast<const f32x4*>(bd);
        for (int j = t; j < 1024; j += 256) {
            f32x4 v = rb[j];
            p += v[0] * v[0] + v[1] * v[1] + v[2] * v[2] + v[3] * v[3];
        }
    }
    red[t] = p;
    __syncthreads();
    for (int s = 128; s > 0; s >>= 1) { if (t < s) red[t] += red[t + s]; __syncthreads(); }
    if (t == 0) {
        if (b < 4096) G[b] = red[0];
        else if (b < 4160) hv[b - 4096] = red[0];
        else ev[0] = red[0];
    }
}

// ---------------- main GEMM: BM=128, BK=32, counted vmcnt(7), 3 blocks/CU
__global__ __launch_bounds__(256, 3) void gemm_kernel(const float* __restrict__ x,
        const unsigned char* __restrict__ Bp, float* __restrict__ Pp,
        int steps, int kslice, int ppstride) {
    __shared__ __align__(16) char lds[51200];    // 2 bufs x (A 16384 + B 9216)
    const int tid = threadIdx.x;
    const int lane = tid & 63, w = tid >> 6;
    const int wm = w >> 1, wn = w & 1;           // 2m x 2n; wn0: cols 0-79, wn1: 80-143
    const int l15 = lane & 15, kg = lane >> 4;
    const int rowbase = blockIdx.x * 128;
    const int ks = blockIdx.y;

    // A staging: 4 instrs/thread; instr i -> linear chunk q = i*256+tid
    const float* xA[4];
#pragma unroll
    for (int i = 0; i < 4; ++i) {
        int q = i * 256 + tid;
        int row = q >> 3, u8 = q & 7;
        int co = (u8 ^ (row & 7)) << 2;
        xA[i] = x + (size_t)(rowbase + row) * 4096 + (size_t)ks * kslice + co;
    }

    f32x4 acc[4][5];
#pragma unroll
    for (int mi = 0; mi < 4; ++mi)
#pragma unroll
        for (int ni = 0; ni < 5; ++ni) acc[mi][ni] = (f32x4){0.f, 0.f, 0.f, 0.f};
    float sxa[4] = {0.f, 0.f, 0.f, 0.f};

#define STAGE(buf, tt) do { \
        const size_t tb_ = (size_t)(ks * steps + (tt)) * 9216; \
        _Pragma("unroll") \
        for (int i_ = 0; i_ < 4; ++i_) \
            gll16(xA[i_] + (tt) * 32, lds + (buf) * 25600 + i_ * 4096 + tid * 16); \
        _Pragma("unroll") \
        for (int j_ = 0; j_ < 2; ++j_) \
            gll16(Bp + tb_ + (size_t)(j_ * 256 + tid) * 16, \
                  lds + (buf) * 25600 + 16384 + (j_ * 256 + tid) * 16); \
        if (kg == 0) \
            gll16(Bp + tb_ + (size_t)(512 + w * 16 + l15) * 16, \
                  lds + (buf) * 25600 + 16384 + (512 + w * 16 + l15) * 16); \
    } while (0)

#define COMPUTE(buf) do { \
        char* A0 = lds + (buf) * 25600; \
        char* B0 = A0 + 16384; \
        bf16x8 bfr[5]; \
        _Pragma("unroll") \
        for (int ni_ = 0; ni_ < 5; ++ni_) { \
            if (wn == 0 || ni_ < 4) { \
                int col_ = wn * 80 + ni_ * 16 + l15; \
                int q_ = (col_ + (col_ >> 2)) & 3; \
                bfr[ni_] = *reinterpret_cast<const bf16x8*>( \
                    B0 + col_ * 64 + ((kg ^ q_) << 4)); \
            } \
        } \
        _Pragma("unroll") \
        for (int mi_ = 0; mi_ < 4; ++mi_) { \
            int row_ = wm * 64 + mi_ * 16 + l15; \
            int e0_ = (kg << 1) ^ (row_ & 7); \
            f32x4 fa_ = *reinterpret_cast<const f32x4*>(A0 + row_ * 128 + (e0_ << 4)); \
            f32x4 fb_ = *reinterpret_cast<const f32x4*>(A0 + row_ * 128 + ((e0_ ^ 1) << 4)); \
            bf16x8 af_; \
            af_[0] = f2bf_s(fa_[0]); af_[1] = f2bf_s(fa_[1]); \
            af_[2] = f2bf_s(fa_[2]); af_[3] = f2bf_s(fa_[3]); \
            af_[4] = f2bf_s(fb_[0]); af_[5] = f2bf_s(fb_[1]); \
            af_[6] = f2bf_s(fb_[2]); af_[7] = f2bf_s(fb_[3]); \
            if (wn == 0) { \
                sxa[mi_] += fa_[0]*fa_[0] + fa_[1]*fa_[1] + fa_[2]*fa_[2] + fa_[3]*fa_[3] \
                          + fb_[0]*fb_[0] + fb_[1]*fb_[1] + fb_[2]*fb_[2] + fb_[3]*fb_[3]; \
            } \
            _Pragma("unroll") \
            for (int ni_ = 0; ni_ < 5; ++ni_) { \
                if (wn == 0 || ni_ < 4) \
                    acc[mi_][ni_] = __builtin_amdgcn_mfma_f32_16x16x32_bf16( \
                        af_, bfr[ni_], acc[mi_][ni_], 0, 0, 0); \
            } \
        } \
    } while (0)

    STAGE(0, 0);
    asm volatile("s_waitcnt vmcnt(0)" ::: "memory");
    __builtin_amdgcn_s_barrier();
    asm volatile("" ::: "memory");
    int cur = 0;
    for (int t = 0; t < steps - 1; ++t) {
        STAGE(cur ^ 1, t + 1);
        asm volatile("s_waitcnt vmcnt(7)" ::: "memory");   // drains step-t loads only
        __builtin_amdgcn_s_barrier();
        asm volatile("" ::: "memory");
        COMPUTE(cur);
        asm volatile("" ::: "memory");
        __builtin_amdgcn_s_barrier();
        cur ^= 1;
    }
    asm volatile("s_waitcnt vmcnt(0)" ::: "memory");
    __builtin_amdgcn_s_barrier();
    asm volatile("" ::: "memory");
    COMPUTE(cur);
#undef STAGE
#undef COMPUTE

    // reduce sx2 across kg groups (lanes 0-15 end with full row sums)
#pragma unroll
    for (int mi = 0; mi < 4; ++mi) {
        sxa[mi] += __shfl_xor(sxa[mi], 16);
        sxa[mi] += __shfl_xor(sxa[mi], 32);
    }

    // ---- coalesced writeback in two 64-row passes via LDS C-tile [64][148]
    float* C = reinterpret_cast<float*>(lds);
#pragma unroll
    for (int pass = 0; pass < 2; ++pass) {
        __syncthreads();
        if (wm == pass) {
#pragma unroll
            for (int mi = 0; mi < 4; ++mi)
#pragma unroll
                for (int ni = 0; ni < 5; ++ni) {
                    if (wn == 0 || ni < 4) {
                        int col = wn * 80 + ni * 16 + l15;
                        if (col != 130) {
#pragma unroll
                            for (int i2 = 0; i2 < 4; ++i2)
                                C[(mi * 16 + kg * 4 + i2) * 148 + col] = acc[mi][ni][i2];
                        }
                    }
                }
        }
        if (wn == 0 && lane < 16) {
#pragma unroll
            for (int mi = 0; mi < 4; ++mi)
                if (wm == pass) C[(mi * 16 + lane) * 148 + 130] = sxa[mi];
        }
        __syncthreads();
#pragma unroll
        for (int i = 0; i < 9; ++i) {
            int idx = tid + 256 * i;
            int r = idx / 36, c4 = idx % 36;
            f32x4 v = *reinterpret_cast<const f32x4*>(C + r * 148 + c4 * 4);
            *reinterpret_cast<f32x4*>(
                Pp + (size_t)(rowbase + pass * 64 + r) * ppstride + ks * 144 + c4 * 4) = v;
        }
    }
}

// ---------------- phase 2: plain [64][64] G, XOR-permuted conflict-free matvec
__global__ __launch_bounds__(256) void phase2_kernel(const float* __restrict__ Pp,
        const float* __restrict__ noise, const float* __restrict__ bem,
        const float* __restrict__ Wds, const float* __restrict__ bes_p,
        const float* __restrict__ bds_p, const float* __restrict__ G,
        const float* __restrict__ hv, const float* __restrict__ ev,
        float* __restrict__ partial, int ksplit, int ppstride) {
    __shared__ float Gl[4096];
    __shared__ float hl[64], wl[64], beml[64];
    __shared__ float zs[4][64];
    __shared__ float red[4];
    int tid = threadIdx.x;
    for (int i = tid; i < 4096; i += 256) Gl[i] = G[i];
    if (tid < 64) { hl[tid] = hv[tid]; wl[tid] = Wds[tid]; beml[tid] = bem[tid]; }
    __syncthreads();
    float bes = bes_p[0], bds = bds_p[0], e = ev[0];
    int wid = tid >> 6, k = tid & 63;
    const int sw = (k & 15) << 2;
    float wacc = 0.f;
#pragma unroll
    for (int rr = 0; rr < 8; ++rr) {
        int row = blockIdx.x * 32 + wid * 8 + rr;
        const float* base = Pp + (size_t)row * ppstride;
        float zmu = beml[k], ck = 0.f, se = bes, dd = 0.f, sx2 = 0.f;
        for (int s = 0; s < ksplit; ++s) {
            const float* b2 = base + s * 144;
            zmu += b2[k]; ck += b2[64 + k];
            se += b2[128]; dd += b2[129]; sx2 += b2[130];
        }
        float nz = noise[(size_t)row * 64 + k];
        float s2 = se * se;
        float z = fmaf(s2, nz, zmu);
        zs[wid][k] = z;
        float t0 = 0.f, t1 = 0.f, t2 = 0.f, t3 = 0.f;
        const float* gr = &Gl[k * 64];
        const float* zr = &zs[wid][0];
#pragma unroll
        for (int jb = 0; jb < 16; ++jb) {
            int p = (jb * 4) ^ sw;
            f32x4 gv = *reinterpret_cast<const f32x4*>(gr + p);
            f32x4 zv = *reinterpret_cast<const f32x4*>(zr + p);
            t0 = fmaf(gv[0], zv[0], t0); t1 = fmaf(gv[1], zv[1], t1);
            t2 = fmaf(gv[2], zv[2], t2); t3 = fmaf(gv[3], zv[3], t3);
        }
        float t = (t0 + t1) + (t2 + t3);
        float ra = z * z;
        float rb = nz * nz;
        float rc = z * wl[k];
        float rd = z * ck;
        float re = z * fmaf(2.f, hl[k], t);
#pragma unroll
        for (int d = 1; d < 64; d <<= 1) {
            ra += __shfl_xor(ra, d); rb += __shfl_xor(rb, d);
            rc += __shfl_xor(rc, d); rd += __shfl_xor(rd, d);
            re += __shfl_xor(re, d);
        }
        float sdec = rc + bds;
        float xxmu = rd + dd;
        float xmu2 = re + e;
        float sq_lik = sx2 - 2.f * xxmu + xmu2;
        float vz = s2 * s2;
        float sd2 = sdec * sdec;
        float vx = sd2 * sd2;
        wacc += 0.5f * (4096.f * LOG2PI + 4096.f * __logf(vx) + sq_lik / vx
                        + ra - 64.f * __logf(vz) - rb);
    }
    if (k == 0) red[wid] = wacc;
    __syncthreads();
    if (tid == 0) partial[blockIdx.x] = red[0] + red[1] + red[2] + red[3];
}

__global__ __launch_bounds__(256) void final_reduce_kernel(const float* __restrict__ partial,
                                                           float* __restrict__ out) {
    __shared__ float red[4];
    int tid = threadIdx.x;
    float v = 0.f;
    for (int i = tid; i < 512; i += 256) v += partial[i];
#pragma unroll
    for (int d = 1; d < 64; d <<= 1) v += __shfl_xor(v, d);
    if ((tid & 63) == 0) red[tid >> 6] = v;
    __syncthreads();
    if (tid == 0) out[0] = red[0] + red[1] + red[2] + red[3];
}

extern "C" void kernel_launch(void* const* d_in, const int* in_sizes, int n_in,
                              void* d_out, int out_size, void* d_ws, size_t ws_size,
                              hipStream_t stream) {
    const float* x     = (const float*)d_in[0];
    const float* noise = (const float*)d_in[1];
    const float* We    = (const float*)d_in[2];
    const float* bem   = (const float*)d_in[3];
    const float* Wes   = (const float*)d_in[4];
    const float* bes   = (const float*)d_in[5];
    const float* Wd    = (const float*)d_in[6];
    const float* bdm   = (const float*)d_in[7];
    const float* Wds   = (const float*)d_in[8];
    const float* bds   = (const float*)d_in[9];

    int ksplit = (ws_size >= 39340544ull) ? 4 : (ws_size >= 20466176ull ? 2 : 1);
    int steps = 128 / ksplit;         // BK=32 tiles per k-slice
    int kslice = steps * 32;
    int ppstride = ksplit * 144;

    char* ws = (char*)d_ws;
    size_t ppbytes = (size_t)16384 * ppstride * 4;
    float* Pp           = (float*)ws;
    unsigned char* Bp   = (unsigned char*)(ws + ppbytes);   // 1,179,648 B used
    float* G            = (float*)(ws + ppbytes + 1572864);
    float* hv           = (float*)(ws + ppbytes + 1572864 + 16384);
    float* ev           = (float*)(ws + ppbytes + 1572864 + 16640);
    float* partial      = (float*)(ws + ppbytes + 1572864 + 16896);

    pack_b_kernel<<<128, 256, 0, stream>>>(We, Wes, Wd, bdm, Bp);
    prep_g_kernel<<<4161, 256, 0, stream>>>(Wd, bdm, G, hv, ev);
    gemm_kernel<<<dim3(128, ksplit), 256, 0, stream>>>(x, Bp, Pp, steps, kslice, ppstride);
    phase2_kernel<<<512, 256, 0, stream>>>(Pp, noise, bem, Wds, bes, bds, G, hv, ev,
                                           partial, ksplit, ppstride);
    final_reduce_kernel<<<1, 256, 0, stream>>>(partial, (float*)d_out);
}

// Round 11
// 105.532 us; speedup vs baseline: 1.1982x; 1.0821x over previous
//
#include <hip/hip_runtime.h>
#include <hip/hip_bf16.h>

#define LOG2PI 1.8378770664093453f

// N=16384, M(K-dim)=4096, K(latent)=64.
// GEMM: Out[n][c] = sum_m x[n][m] * Bcat[c][m], staged cols c in [0,144):
//   c 0-63: W_enc_mu col, 64-127: W_dec_mu row (c-64), 128: W_enc_sigma, 129: b_dec_mu.
// Split-K: KSPLIT slices of m; partials Pp[row][ks][144] (stride ppstride).
// col 130 of each partial = per-slice sum(x^2); cols 131-143 zero.
//
// Bp layout: per k-tile kt (32 m-values, 128 tiles), a 9216-B linear LDS image:
//   offset col*64 + u*16 holds Bcat[col][kt*32 + (u^q(col))*8 .. +8] as 8 bf16,
//   q(col) = (col + (col>>2)) & 3  (2-way-free ds_read banking). 144 cols.
// A LDS image per step: row*128 + u8*16 holds x[row][t*32 + (u8^(row&7))*4 ..+4] fp32.
// BM=128, BK=32, 4 waves (2m x 2n asym: 5/4 frags), 3 blocks/CU.
// K-tiles processed in per-block rotated order (channel de-aliasing stagger).

typedef __attribute__((ext_vector_type(8))) short bf16x8;
typedef __attribute__((ext_vector_type(4))) float f32x4;

__device__ __forceinline__ unsigned short f2bf(float f) {
    unsigned int u = __builtin_bit_cast(unsigned int, f);
    u += 0x7FFFu + ((u >> 16) & 1u);
    return (unsigned short)(u >> 16);
}
__device__ __forceinline__ short f2bf_s(float f) {
    return (short)__builtin_bit_cast(unsigned short, __float2bfloat16(f));
}
__device__ __forceinline__ void gll16(const void* g, void* l) {
    __builtin_amdgcn_global_load_lds(
        (const __attribute__((address_space(1))) void*)g,
        (__attribute__((address_space(3))) void*)l, 16, 0, 0);
}

// ---------------- pack B (coalesced): one block per k-tile of 32 m-values
__global__ __launch_bounds__(256) void pack_b_kernel(const float* __restrict__ We,
        const float* __restrict__ Wes, const float* __restrict__ Wd,
        const float* __restrict__ bd, unsigned char* __restrict__ Bp) {
    __shared__ float WeL[2048];   // [32 m][64 c]
    __shared__ float WdL[2048];   // [64 r][32 m]
    __shared__ float WesL[32], bdL[32];
    const int kt = blockIdx.x;    // [0,128)
    const int t = threadIdx.x;
#pragma unroll
    for (int i = 0; i < 2; ++i) {
        int q = t + 256 * i;
        *reinterpret_cast<f32x4*>(WeL + q * 4) =
            *reinterpret_cast<const f32x4*>(We + (size_t)kt * 2048 + q * 4);
    }
#pragma unroll
    for (int i = 0; i < 2; ++i) {
        int f = t + 256 * i;
        int r = f >> 3, s4 = f & 7;
        *reinterpret_cast<f32x4*>(WdL + r * 32 + s4 * 4) =
            *reinterpret_cast<const f32x4*>(Wd + (size_t)r * 4096 + kt * 32 + s4 * 4);
    }
    if (t < 8) {
        *reinterpret_cast<f32x4*>(WesL + t * 4) =
            *reinterpret_cast<const f32x4*>(Wes + kt * 32 + t * 4);
    } else if (t < 16) {
        int q = t - 8;
        *reinterpret_cast<f32x4*>(bdL + q * 4) =
            *reinterpret_cast<const f32x4*>(bd + kt * 32 + q * 4);
    }
    __syncthreads();
#pragma unroll
    for (int i = 0; i < 3; ++i) {
        int cidx = t + 256 * i;            // [0,576) = col*4 + u
        if (cidx < 576) {
            int col = cidx >> 2, u = cidx & 3;
            int ku = u ^ ((col + (col >> 2)) & 3);
            unsigned short out[8];
#pragma unroll
            for (int j = 0; j < 8; ++j) {
                int ml = ku * 8 + j;
                float v = 0.f;
                if (col < 64)        v = WeL[ml * 64 + col];
                else if (col < 128)  v = WdL[(col - 64) * 32 + ml];
                else if (col == 128) v = WesL[ml];
                else if (col == 129) v = bdL[ml];
                out[j] = f2bf(v);
            }
            *reinterpret_cast<uint4*>(Bp + ((size_t)kt * 576 + cidx) * 16) =
                *reinterpret_cast<uint4*>(out);
        }
    }
}

// ---------------- prep (coalesced): G pairs + h + e via row-dot blocks
__global__ __launch_bounds__(256) void prep_g_kernel(const float* __restrict__ Wd,
        const float* __restrict__ bd, float* __restrict__ G,
        float* __restrict__ hv, float* __restrict__ ev) {
    __shared__ float red[256];
    const int b = blockIdx.x, t = threadIdx.x;
    float p = 0.f;
    if (b < 4096) {
        int a = b >> 6, c = b & 63;
        const f32x4* ra = reinterpret_cast<const f32x4*>(Wd + (size_t)a * 4096);
        const f32x4* rc = reinterpret_cast<const f32x4*>(Wd + (size_t)c * 4096);
        for (int j = t; j < 1024; j += 256) {
            f32x4 u = ra[j], v = rc[j];
            p += u[0] * v[0] + u[1] * v[1] + u[2] * v[2] + u[3] * v[3];
        }
    } else if (b < 4160) {
        int a = b - 4096;
        const f32x4* ra = reinterpret_cast<const f32x4*>(Wd + (size_t)a * 4096);
        const f32x4* rb = reinterpret_cast<const f32x4*>(bd);
        for (int j = t; j < 1024; j += 256) {
            f32x4 u = ra[j], v = rb[j];
            p += u[0] * v[0] + u[1] * v[1] + u[2] * v[2] + u[3] * v[3];
        }
    } else {
        const f32x4* rb = reinterpret_cast<const f32x4*>(bd);
        for (int j = t; j < 1024; j += 256) {
            f32x4 v = rb[j];
            p += v[0] * v[0] + v[1] * v[1] + v[2] * v[2] + v[3] * v[3];
        }
    }
    red[t] = p;
    __syncthreads();
    for (int s = 128; s > 0; s >>= 1) { if (t < s) red[t] += red[t + s]; __syncthreads(); }
    if (t == 0) {
        if (b < 4096) G[b] = red[0];
        else if (b < 4160) hv[b - 4096] = red[0];
        else ev[0] = red[0];
    }
}

// ---------------- main GEMM: BM=128, BK=32, counted vmcnt(7), k-phase stagger
__global__ __launch_bounds__(256, 3) void gemm_kernel(const float* __restrict__ x,
        const unsigned char* __restrict__ Bp, float* __restrict__ Pp,
        int steps, int kslice, int ppstride) {
    __shared__ __align__(16) char lds[51200];    // 2 bufs x (A 16384 + B 9216)
    const int tid = threadIdx.x;
    const int lane = tid & 63, w = tid >> 6;
    const int wm = w >> 1, wn = w & 1;           // 2m x 2n; wn0: cols 0-79, wn1: 80-143
    const int l15 = lane & 15, kg = lane >> 4;
    const int rowbase = blockIdx.x * 128;
    const int ks = blockIdx.y;

    // A staging: 4 instrs/thread; instr i -> linear chunk q = i*256+tid
    const float* xA[4];
#pragma unroll
    for (int i = 0; i < 4; ++i) {
        int q = i * 256 + tid;
        int row = q >> 3, u8 = q & 7;
        int co = (u8 ^ (row & 7)) << 2;
        xA[i] = x + (size_t)(rowbase + row) * 4096 + (size_t)ks * kslice + co;
    }

    f32x4 acc[4][5];
#pragma unroll
    for (int mi = 0; mi < 4; ++mi)
#pragma unroll
        for (int ni = 0; ni < 5; ++ni) acc[mi][ni] = (f32x4){0.f, 0.f, 0.f, 0.f};
    float sxa[4] = {0.f, 0.f, 0.f, 0.f};

#define STAGE(buf, tt) do { \
        const size_t tb_ = (size_t)(ks * steps + (tt)) * 9216; \
        _Pragma("unroll") \
        for (int i_ = 0; i_ < 4; ++i_) \
            gll16(xA[i_] + (tt) * 32, lds + (buf) * 25600 + i_ * 4096 + tid * 16); \
        _Pragma("unroll") \
        for (int j_ = 0; j_ < 2; ++j_) \
            gll16(Bp + tb_ + (size_t)(j_ * 256 + tid) * 16, \
                  lds + (buf) * 25600 + 16384 + (j_ * 256 + tid) * 16); \
        if (kg == 0) \
            gll16(Bp + tb_ + (size_t)(512 + w * 16 + l15) * 16, \
                  lds + (buf) * 25600 + 16384 + (512 + w * 16 + l15) * 16); \
    } while (0)

#define COMPUTE(buf) do { \
        char* A0 = lds + (buf) * 25600; \
        char* B0 = A0 + 16384; \
        bf16x8 bfr[5]; \
        _Pragma("unroll") \
        for (int ni_ = 0; ni_ < 5; ++ni_) { \
            if (wn == 0 || ni_ < 4) { \
                int col_ = wn * 80 + ni_ * 16 + l15; \
                int q_ = (col_ + (col_ >> 2)) & 3; \
                bfr[ni_] = *reinterpret_cast<const bf16x8*>( \
                    B0 + col_ * 64 + ((kg ^ q_) << 4)); \
            } \
        } \
        _Pragma("unroll") \
        for (int mi_ = 0; mi_ < 4; ++mi_) { \
            int row_ = wm * 64 + mi_ * 16 + l15; \
            int e0_ = (kg << 1) ^ (row_ & 7); \
            f32x4 fa_ = *reinterpret_cast<const f32x4*>(A0 + row_ * 128 + (e0_ << 4)); \
            f32x4 fb_ = *reinterpret_cast<const f32x4*>(A0 + row_ * 128 + ((e0_ ^ 1) << 4)); \
            bf16x8 af_; \
            af_[0] = f2bf_s(fa_[0]); af_[1] = f2bf_s(fa_[1]); \
            af_[2] = f2bf_s(fa_[2]); af_[3] = f2bf_s(fa_[3]); \
            af_[4] = f2bf_s(fb_[0]); af_[5] = f2bf_s(fb_[1]); \
            af_[6] = f2bf_s(fb_[2]); af_[7] = f2bf_s(fb_[3]); \
            if (wn == 0) { \
                sxa[mi_] += fa_[0]*fa_[0] + fa_[1]*fa_[1] + fa_[2]*fa_[2] + fa_[3]*fa_[3] \
                          + fb_[0]*fb_[0] + fb_[1]*fb_[1] + fb_[2]*fb_[2] + fb_[3]*fb_[3]; \
            } \
            _Pragma("unroll") \
            for (int ni_ = 0; ni_ < 5; ++ni_) { \
                if (wn == 0 || ni_ < 4) \
                    acc[mi_][ni_] = __builtin_amdgcn_mfma_f32_16x16x32_bf16( \
                        af_, bfr[ni_], acc[mi_][ni_], 0, 0, 0); \
            } \
        } \
    } while (0)

    // channel-de-aliasing stagger: rotate k-tile order per block
    const int phase = (blockIdx.x + ks * 8) & (steps - 1);
    int tp = phase;
    STAGE(0, tp);
    asm volatile("s_waitcnt vmcnt(0)" ::: "memory");
    __builtin_amdgcn_s_barrier();
    asm volatile("" ::: "memory");
    int cur = 0;
    for (int t = 0; t < steps - 1; ++t) {
        int tpn = (tp + 1 == steps) ? 0 : tp + 1;
        STAGE(cur ^ 1, tpn);
        asm volatile("s_waitcnt vmcnt(7)" ::: "memory");   // drains step-t loads only
        __builtin_amdgcn_s_barrier();
        asm volatile("" ::: "memory");
        COMPUTE(cur);
        asm volatile("" ::: "memory");
        __builtin_amdgcn_s_barrier();
        cur ^= 1;
        tp = tpn;
    }
    asm volatile("s_waitcnt vmcnt(0)" ::: "memory");
    __builtin_amdgcn_s_barrier();
    asm volatile("" ::: "memory");
    COMPUTE(cur);
#undef STAGE
#undef COMPUTE

    // reduce sx2 across kg groups (lanes 0-15 end with full row sums)
#pragma unroll
    for (int mi = 0; mi < 4; ++mi) {
        sxa[mi] += __shfl_xor(sxa[mi], 16);
        sxa[mi] += __shfl_xor(sxa[mi], 32);
    }

    // ---- coalesced writeback in two 64-row passes via LDS C-tile [64][148]
    float* C = reinterpret_cast<float*>(lds);
#pragma unroll
    for (int pass = 0; pass < 2; ++pass) {
        __syncthreads();
        if (wm == pass) {
#pragma unroll
            for (int mi = 0; mi < 4; ++mi)
#pragma unroll
                for (int ni = 0; ni < 5; ++ni) {
                    if (wn == 0 || ni < 4) {
                        int col = wn * 80 + ni * 16 + l15;
                        if (col != 130) {
#pragma unroll
                            for (int i2 = 0; i2 < 4; ++i2)
                                C[(mi * 16 + kg * 4 + i2) * 148 + col] = acc[mi][ni][i2];
                        }
                    }
                }
        }
        if (wn == 0 && lane < 16) {
#pragma unroll
            for (int mi = 0; mi < 4; ++mi)
                if (wm == pass) C[(mi * 16 + lane) * 148 + 130] = sxa[mi];
        }
        __syncthreads();
#pragma unroll
        for (int i = 0; i < 9; ++i) {
            int idx = tid + 256 * i;
            int r = idx / 36, c4 = idx % 36;
            f32x4 v = *reinterpret_cast<const f32x4*>(C + r * 148 + c4 * 4);
            *reinterpret_cast<f32x4*>(
                Pp + (size_t)(rowbase + pass * 64 + r) * ppstride + ks * 144 + c4 * 4) = v;
        }
    }
}

// ---------------- phase 2: plain [64][64] G, XOR-permuted conflict-free matvec
__global__ __launch_bounds__(256) void phase2_kernel(const float* __restrict__ Pp,
        const float* __restrict__ noise, const float* __restrict__ bem,
        const float* __restrict__ Wds, const float* __restrict__ bes_p,
        const float* __restrict__ bds_p, const float* __restrict__ G,
        const float* __restrict__ hv, const float* __restrict__ ev,
        float* __restrict__ partial, int ksplit, int ppstride) {
    __shared__ float Gl[4096];
    __shared__ float hl[64], wl[64], beml[64];
    __shared__ float zs[4][64];
    __shared__ float red[4];
    int tid = threadIdx.x;
    for (int i = tid; i < 4096; i += 256) Gl[i] = G[i];
    if (tid < 64) { hl[tid] = hv[tid]; wl[tid] = Wds[tid]; beml[tid] = bem[tid]; }
    __syncthreads();
    float bes = bes_p[0], bds = bds_p[0], e = ev[0];
    int wid = tid >> 6, k = tid & 63;
    const int sw = (k & 15) << 2;
    float wacc = 0.f;
#pragma unroll
    for (int rr = 0; rr < 8; ++rr) {
        int row = blockIdx.x * 32 + wid * 8 + rr;
        const float* base = Pp + (size_t)row * ppstride;
        float zmu = beml[k], ck = 0.f, se = bes, dd = 0.f, sx2 = 0.f;
        for (int s = 0; s < ksplit; ++s) {
            const float* b2 = base + s * 144;
            zmu += b2[k]; ck += b2[64 + k];
            se += b2[128]; dd += b2[129]; sx2 += b2[130];
        }
        float nz = noise[(size_t)row * 64 + k];
        float s2 = se * se;
        float z = fmaf(s2, nz, zmu);
        zs[wid][k] = z;
        float t0 = 0.f, t1 = 0.f, t2 = 0.f, t3 = 0.f;
        const float* gr = &Gl[k * 64];
        const float* zr = &zs[wid][0];
#pragma unroll
        for (int jb = 0; jb < 16; ++jb) {
            int p = (jb * 4) ^ sw;
            f32x4 gv = *reinterpret_cast<const f32x4*>(gr + p);
            f32x4 zv = *reinterpret_cast<const f32x4*>(zr + p);
            t0 = fmaf(gv[0], zv[0], t0); t1 = fmaf(gv[1], zv[1], t1);
            t2 = fmaf(gv[2], zv[2], t2); t3 = fmaf(gv[3], zv[3], t3);
        }
        float t = (t0 + t1) + (t2 + t3);
        float ra = z * z;
        float rb = nz * nz;
        float rc = z * wl[k];
        float rd = z * ck;
        float re = z * fmaf(2.f, hl[k], t);
#pragma unroll
        for (int d = 1; d < 64; d <<= 1) {
            ra += __shfl_xor(ra, d); rb += __shfl_xor(rb, d);
            rc += __shfl_xor(rc, d); rd += __shfl_xor(rd, d);
            re += __shfl_xor(re, d);
        }
        float sdec = rc + bds;
        float xxmu = rd + dd;
        float xmu2 = re + e;
        float sq_lik = sx2 - 2.f * xxmu + xmu2;
        float vz = s2 * s2;
        float sd2 = sdec * sdec;
        float vx = sd2 * sd2;
        wacc += 0.5f * (4096.f * LOG2PI + 4096.f * __logf(vx) + sq_lik / vx
                        + ra - 64.f * __logf(vz) - rb);
    }
    if (k == 0) red[wid] = wacc;
    __syncthreads();
    if (tid == 0) partial[blockIdx.x] = red[0] + red[1] + red[2] + red[3];
}

__global__ __launch_bounds__(256) void final_reduce_kernel(const float* __restrict__ partial,
                                                           float* __restrict__ out) {
    __shared__ float red[4];
    int tid = threadIdx.x;
    float v = 0.f;
    for (int i = tid; i < 512; i += 256) v += partial[i];
#pragma unroll
    for (int d = 1; d < 64; d <<= 1) v += __shfl_xor(v, d);
    if ((tid & 63) == 0) red[tid >> 6] = v;
    __syncthreads();
    if (tid == 0) out[0] = red[0] + red[1] + red[2] + red[3];
}

extern "C" void kernel_launch(void* const* d_in, const int* in_sizes, int n_in,
                              void* d_out, int out_size, void* d_ws, size_t ws_size,
                              hipStream_t stream) {
    const float* x     = (const float*)d_in[0];
    const float* noise = (const float*)d_in[1];
    const float* We    = (const float*)d_in[2];
    const float* bem   = (const float*)d_in[3];
    const float* Wes   = (const float*)d_in[4];
    const float* bes   = (const float*)d_in[5];
    const float* Wd    = (const float*)d_in[6];
    const float* bdm   = (const float*)d_in[7];
    const float* Wds   = (const float*)d_in[8];
    const float* bds   = (const float*)d_in[9];

    int ksplit = (ws_size >= 39340544ull) ? 4 : (ws_size >= 20466176ull ? 2 : 1);
    int steps = 128 / ksplit;         // BK=32 tiles per k-slice
    int kslice = steps * 32;
    int ppstride = ksplit * 144;

    char* ws = (char*)d_ws;
    size_t ppbytes = (size_t)16384 * ppstride * 4;
    float* Pp           = (float*)ws;
    unsigned char* Bp   = (unsigned char*)(ws + ppbytes);   // 1,179,648 B used
    float* G            = (float*)(ws + ppbytes + 1572864);
    float* hv           = (float*)(ws + ppbytes + 1572864 + 16384);
    float* ev           = (float*)(ws + ppbytes + 1572864 + 16640);
    float* partial      = (float*)(ws + ppbytes + 1572864 + 16896);

    pack_b_kernel<<<128, 256, 0, stream>>>(We, Wes, Wd, bdm, Bp);
    prep_g_kernel<<<4161, 256, 0, stream>>>(Wd, bdm, G, hv, ev);
    gemm_kernel<<<dim3(128, ksplit), 256, 0, stream>>>(x, Bp, Pp, steps, kslice, ppstride);
    phase2_kernel<<<512, 256, 0, stream>>>(Pp, noise, bem, Wds, bes, bds, G, hv, ev,
                                           partial, ksplit, ppstride);
    final_reduce_kernel<<<1, 256, 0, stream>>>(partial, (float*)d_out);
}

// Round 12
// 101.463 us; speedup vs baseline: 1.2463x; 1.0401x over previous
//
#include <hip/hip_runtime.h>
#include <hip/hip_bf16.h>

#define LOG2PI 1.8378770664093453f

// N=16384, M(K-dim)=4096, K(latent)=64.
// GEMM: Out[n][c] = sum_m x[n][m] * Bcat[c][m], staged cols c in [0,144):
//   c 0-63: W_enc_mu col, 64-127: W_dec_mu row (c-64), 128: W_enc_sigma, 129: b_dec_mu.
// Split-K: KSPLIT slices of m; partials Pp[row][ks][144] (stride ppstride).
// col 130 of each partial = per-slice sum(x^2); cols 131-143 zero.
//
// Bp layout: per k-tile kt (32 m-values, 128 tiles), a 9216-B linear LDS image:
//   offset col*64 + u*16 holds Bcat[col][kt*32 + (u^q(col))*8 .. +8] as 8 bf16,
//   q(col) = (col + (col>>2)) & 3  (2-way-free ds_read banking). 144 cols.
// A LDS image per step: row*128 + u8*16 holds x[row][t*32 + (u8^(row&7))*4 ..+4] fp32.
// BM=128, BK=32, 4 waves (2m x 2n asym: 5/4 frags).
// TRIPLE-buffered, depth-2 prefetch (vmcnt(14)), 2 blocks/CU, k-phase stagger.

typedef __attribute__((ext_vector_type(8))) short bf16x8;
typedef __attribute__((ext_vector_type(4))) float f32x4;

__device__ __forceinline__ unsigned short f2bf(float f) {
    unsigned int u = __builtin_bit_cast(unsigned int, f);
    u += 0x7FFFu + ((u >> 16) & 1u);
    return (unsigned short)(u >> 16);
}
__device__ __forceinline__ short f2bf_s(float f) {
    return (short)__builtin_bit_cast(unsigned short, __float2bfloat16(f));
}
__device__ __forceinline__ void gll16(const void* g, void* l) {
    __builtin_amdgcn_global_load_lds(
        (const __attribute__((address_space(1))) void*)g,
        (__attribute__((address_space(3))) void*)l, 16, 0, 0);
}

// ---------------- merged prep: blocks 0-127 pack B; blocks 128+ compute G/h/e
__global__ __launch_bounds__(256) void prep_kernel(const float* __restrict__ We,
        const float* __restrict__ Wes, const float* __restrict__ Wd,
        const float* __restrict__ bd, unsigned char* __restrict__ Bp,
        float* __restrict__ G, float* __restrict__ hv, float* __restrict__ ev) {
    __shared__ float WeL[2048];   // [32 m][64 c]
    __shared__ float WdL[2048];   // [64 r][32 m]
    __shared__ float WesL[32], bdL[32];
    __shared__ float red[256];
    const int t = threadIdx.x;
    if (blockIdx.x < 128) {
        const int kt = blockIdx.x;    // [0,128)
#pragma unroll
        for (int i = 0; i < 2; ++i) {
            int q = t + 256 * i;
            *reinterpret_cast<f32x4*>(WeL + q * 4) =
                *reinterpret_cast<const f32x4*>(We + (size_t)kt * 2048 + q * 4);
        }
#pragma unroll
        for (int i = 0; i < 2; ++i) {
            int f = t + 256 * i;
            int r = f >> 3, s4 = f & 7;
            *reinterpret_cast<f32x4*>(WdL + r * 32 + s4 * 4) =
                *reinterpret_cast<const f32x4*>(Wd + (size_t)r * 4096 + kt * 32 + s4 * 4);
        }
        if (t < 8) {
            *reinterpret_cast<f32x4*>(WesL + t * 4) =
                *reinterpret_cast<const f32x4*>(Wes + kt * 32 + t * 4);
        } else if (t < 16) {
            int q = t - 8;
            *reinterpret_cast<f32x4*>(bdL + q * 4) =
                *reinterpret_cast<const f32x4*>(bd + kt * 32 + q * 4);
        }
        __syncthreads();
#pragma unroll
        for (int i = 0; i < 3; ++i) {
            int cidx = t + 256 * i;            // [0,576) = col*4 + u
            if (cidx < 576) {
                int col = cidx >> 2, u = cidx & 3;
                int ku = u ^ ((col + (col >> 2)) & 3);
                unsigned short out[8];
#pragma unroll
                for (int j = 0; j < 8; ++j) {
                    int ml = ku * 8 + j;
                    float v = 0.f;
                    if (col < 64)        v = WeL[ml * 64 + col];
                    else if (col < 128)  v = WdL[(col - 64) * 32 + ml];
                    else if (col == 128) v = WesL[ml];
                    else if (col == 129) v = bdL[ml];
                    out[j] = f2bf(v);
                }
                *reinterpret_cast<uint4*>(Bp + ((size_t)kt * 576 + cidx) * 16) =
                    *reinterpret_cast<uint4*>(out);
            }
        }
        return;
    }
    // ---- G / h / e part
    const int b = blockIdx.x - 128;
    float p = 0.f;
    if (b < 4096) {
        int a = b >> 6, c = b & 63;
        const f32x4* ra = reinterpret_cast<const f32x4*>(Wd + (size_t)a * 4096);
        const f32x4* rc = reinterpret_cast<const f32x4*>(Wd + (size_t)c * 4096);
        for (int j = t; j < 1024; j += 256) {
            f32x4 u = ra[j], v = rc[j];
            p += u[0] * v[0] + u[1] * v[1] + u[2] * v[2] + u[3] * v[3];
        }
    } else if (b < 4160) {
        int a = b - 4096;
        const f32x4* ra = reinterpret_cast<const f32x4*>(Wd + (size_t)a * 4096);
        const f32x4* rb = reinterpret_cast<const f32x4*>(bd);
        for (int j = t; j < 1024; j += 256) {
            f32x4 u = ra[j], v = rb[j];
            p += u[0] * v[0] + u[1] * v[1] + u[2] * v[2] + u[3] * v[3];
        }
    } else {
        const f32x4* rb = reinterpret_cast<const f32x4*>(bd);
        for (int j = t; j < 1024; j += 256) {
            f32x4 v = rb[j];
            p += v[0] * v[0] + v[1] * v[1] + v[2] * v[2] + v[3] * v[3];
        }
    }
    red[t] = p;
    __syncthreads();
    for (int s = 128; s > 0; s >>= 1) { if (t < s) red[t] += red[t + s]; __syncthreads(); }
    if (t == 0) {
        if (b < 4096) G[b] = red[0];
        else if (b < 4160) hv[b - 4096] = red[0];
        else ev[0] = red[0];
    }
}

// ---------------- main GEMM: BM=128, BK=32, triple-buffer depth-2, stagger
__global__ __launch_bounds__(256, 2) void gemm_kernel(const float* __restrict__ x,
        const unsigned char* __restrict__ Bp, float* __restrict__ Pp,
        int steps, int kslice, int ppstride) {
    __shared__ __align__(16) char lds[76800];    // 3 bufs x (A 16384 + B 9216)
    const int tid = threadIdx.x;
    const int lane = tid & 63, w = tid >> 6;
    const int wm = w >> 1, wn = w & 1;           // 2m x 2n; wn0: cols 0-79, wn1: 80-143
    const int l15 = lane & 15, kg = lane >> 4;
    const int rowbase = blockIdx.x * 128;
    const int ks = blockIdx.y;

    // A staging: 4 instrs/thread; instr i -> linear chunk q = i*256+tid
    const float* xA[4];
#pragma unroll
    for (int i = 0; i < 4; ++i) {
        int q = i * 256 + tid;
        int row = q >> 3, u8 = q & 7;
        int co = (u8 ^ (row & 7)) << 2;
        xA[i] = x + (size_t)(rowbase + row) * 4096 + (size_t)ks * kslice + co;
    }

    f32x4 acc[4][5];
#pragma unroll
    for (int mi = 0; mi < 4; ++mi)
#pragma unroll
        for (int ni = 0; ni < 5; ++ni) acc[mi][ni] = (f32x4){0.f, 0.f, 0.f, 0.f};
    float sxa[4] = {0.f, 0.f, 0.f, 0.f};

#define STAGE(buf, tt) do { \
        char* Lb_ = lds + (buf) * 25600; \
        const size_t tb_ = (size_t)(ks * steps + (tt)) * 9216; \
        _Pragma("unroll") \
        for (int i_ = 0; i_ < 4; ++i_) \
            gll16(xA[i_] + (tt) * 32, Lb_ + i_ * 4096 + tid * 16); \
        _Pragma("unroll") \
        for (int j_ = 0; j_ < 2; ++j_) \
            gll16(Bp + tb_ + (size_t)(j_ * 256 + tid) * 16, \
                  Lb_ + 16384 + (j_ * 256 + tid) * 16); \
        if (kg == 0) \
            gll16(Bp + tb_ + (size_t)(512 + w * 16 + l15) * 16, \
                  Lb_ + 16384 + (512 + w * 16 + l15) * 16); \
    } while (0)

#define COMPUTE(buf) do { \
        char* A0 = lds + (buf) * 25600; \
        char* B0 = A0 + 16384; \
        bf16x8 bfr[5]; \
        _Pragma("unroll") \
        for (int ni_ = 0; ni_ < 5; ++ni_) { \
            if (wn == 0 || ni_ < 4) { \
                int col_ = wn * 80 + ni_ * 16 + l15; \
                int q_ = (col_ + (col_ >> 2)) & 3; \
                bfr[ni_] = *reinterpret_cast<const bf16x8*>( \
                    B0 + col_ * 64 + ((kg ^ q_) << 4)); \
            } \
        } \
        _Pragma("unroll") \
        for (int mi_ = 0; mi_ < 4; ++mi_) { \
            int row_ = wm * 64 + mi_ * 16 + l15; \
            int e0_ = (kg << 1) ^ (row_ & 7); \
            f32x4 fa_ = *reinterpret_cast<const f32x4*>(A0 + row_ * 128 + (e0_ << 4)); \
            f32x4 fb_ = *reinterpret_cast<const f32x4*>(A0 + row_ * 128 + ((e0_ ^ 1) << 4)); \
            bf16x8 af_; \
            af_[0] = f2bf_s(fa_[0]); af_[1] = f2bf_s(fa_[1]); \
            af_[2] = f2bf_s(fa_[2]); af_[3] = f2bf_s(fa_[3]); \
            af_[4] = f2bf_s(fb_[0]); af_[5] = f2bf_s(fb_[1]); \
            af_[6] = f2bf_s(fb_[2]); af_[7] = f2bf_s(fb_[3]); \
            if (wn == 0) { \
                sxa[mi_] += fa_[0]*fa_[0] + fa_[1]*fa_[1] + fa_[2]*fa_[2] + fa_[3]*fa_[3] \
                          + fb_[0]*fb_[0] + fb_[1]*fb_[1] + fb_[2]*fb_[2] + fb_[3]*fb_[3]; \
            } \
            _Pragma("unroll") \
            for (int ni_ = 0; ni_ < 5; ++ni_) { \
                if (wn == 0 || ni_ < 4) \
                    acc[mi_][ni_] = __builtin_amdgcn_mfma_f32_16x16x32_bf16( \
                        af_, bfr[ni_], acc[mi_][ni_], 0, 0, 0); \
            } \
        } \
    } while (0)

    // channel-de-aliasing stagger: rotate k-tile order per block
    const int phase = (blockIdx.x + ks * 8) & (steps - 1);
    int tp0 = phase;
    int tpn = (tp0 + 1 == steps) ? 0 : tp0 + 1;
    STAGE(0, tp0);
    STAGE(1, tpn);
    int cur = 0;
    for (int t = 0; t < steps; ++t) {
        if (t + 2 < steps) {
            tpn = (tpn + 1 == steps) ? 0 : tpn + 1;
            int b2 = (cur == 0) ? 2 : cur - 1;        // (cur+2)%3
            STAGE(b2, tpn);
            asm volatile("s_waitcnt vmcnt(14)" ::: "memory");  // step-t loads done
        } else if (t + 2 == steps) {
            asm volatile("s_waitcnt vmcnt(7)" ::: "memory");
        } else {
            asm volatile("s_waitcnt vmcnt(0)" ::: "memory");
        }
        __builtin_amdgcn_s_barrier();
        asm volatile("" ::: "memory");
        COMPUTE(cur);
        asm volatile("" ::: "memory");
        __builtin_amdgcn_s_barrier();
        cur = (cur == 2) ? 0 : cur + 1;
    }
#undef STAGE
#undef COMPUTE

    // reduce sx2 across kg groups (lanes 0-15 end with full row sums)
#pragma unroll
    for (int mi = 0; mi < 4; ++mi) {
        sxa[mi] += __shfl_xor(sxa[mi], 16);
        sxa[mi] += __shfl_xor(sxa[mi], 32);
    }

    // ---- coalesced writeback in two 64-row passes via LDS C-tile [64][148]
    float* C = reinterpret_cast<float*>(lds);
#pragma unroll
    for (int pass = 0; pass < 2; ++pass) {
        __syncthreads();
        if (wm == pass) {
#pragma unroll
            for (int mi = 0; mi < 4; ++mi)
#pragma unroll
                for (int ni = 0; ni < 5; ++ni) {
                    if (wn == 0 || ni < 4) {
                        int col = wn * 80 + ni * 16 + l15;
                        if (col != 130) {
#pragma unroll
                            for (int i2 = 0; i2 < 4; ++i2)
                                C[(mi * 16 + kg * 4 + i2) * 148 + col] = acc[mi][ni][i2];
                        }
                    }
                }
        }
        if (wn == 0 && lane < 16) {
#pragma unroll
            for (int mi = 0; mi < 4; ++mi)
                if (wm == pass) C[(mi * 16 + lane) * 148 + 130] = sxa[mi];
        }
        __syncthreads();
#pragma unroll
        for (int i = 0; i < 9; ++i) {
            int idx = tid + 256 * i;
            int r = idx / 36, c4 = idx % 36;
            f32x4 v = *reinterpret_cast<const f32x4*>(C + r * 148 + c4 * 4);
            *reinterpret_cast<f32x4*>(
                Pp + (size_t)(rowbase + pass * 64 + r) * ppstride + ks * 144 + c4 * 4) = v;
        }
    }
}

// ---------------- phase 2: plain [64][64] G, XOR-permuted conflict-free matvec
__global__ __launch_bounds__(256) void phase2_kernel(const float* __restrict__ Pp,
        const float* __restrict__ noise, const float* __restrict__ bem,
        const float* __restrict__ Wds, const float* __restrict__ bes_p,
        const float* __restrict__ bds_p, const float* __restrict__ G,
        const float* __restrict__ hv, const float* __restrict__ ev,
        float* __restrict__ partial, int ksplit, int ppstride) {
    __shared__ float Gl[4096];
    __shared__ float hl[64], wl[64], beml[64];
    __shared__ float zs[4][64];
    __shared__ float red[4];
    int tid = threadIdx.x;
    for (int i = tid; i < 4096; i += 256) Gl[i] = G[i];
    if (tid < 64) { hl[tid] = hv[tid]; wl[tid] = Wds[tid]; beml[tid] = bem[tid]; }
    __syncthreads();
    float bes = bes_p[0], bds = bds_p[0], e = ev[0];
    int wid = tid >> 6, k = tid & 63;
    const int sw = (k & 15) << 2;
    float wacc = 0.f;
#pragma unroll
    for (int rr = 0; rr < 8; ++rr) {
        int row = blockIdx.x * 32 + wid * 8 + rr;
        const float* base = Pp + (size_t)row * ppstride;
        float zmu = beml[k], ck = 0.f, se = bes, dd = 0.f, sx2 = 0.f;
        for (int s = 0; s < ksplit; ++s) {
            const float* b2 = base + s * 144;
            zmu += b2[k]; ck += b2[64 + k];
            se += b2[128]; dd += b2[129]; sx2 += b2[130];
        }
        float nz = noise[(size_t)row * 64 + k];
        float s2 = se * se;
        float z = fmaf(s2, nz, zmu);
        zs[wid][k] = z;
        float t0 = 0.f, t1 = 0.f, t2 = 0.f, t3 = 0.f;
        const float* gr = &Gl[k * 64];
        const float* zr = &zs[wid][0];
#pragma unroll
        for (int jb = 0; jb < 16; ++jb) {
            int p = (jb * 4) ^ sw;
            f32x4 gv = *reinterpret_cast<const f32x4*>(gr + p);
            f32x4 zv = *reinterpret_cast<const f32x4*>(zr + p);
            t0 = fmaf(gv[0], zv[0], t0); t1 = fmaf(gv[1], zv[1], t1);
            t2 = fmaf(gv[2], zv[2], t2); t3 = fmaf(gv[3], zv[3], t3);
        }
        float t = (t0 + t1) + (t2 + t3);
        float ra = z * z;
        float rb = nz * nz;
        float rc = z * wl[k];
        float rd = z * ck;
        float re = z * fmaf(2.f, hl[k], t);
#pragma unroll
        for (int d = 1; d < 64; d <<= 1) {
            ra += __shfl_xor(ra, d); rb += __shfl_xor(rb, d);
            rc += __shfl_xor(rc, d); rd += __shfl_xor(rd, d);
            re += __shfl_xor(re, d);
        }
        float sdec = rc + bds;
        float xxmu = rd + dd;
        float xmu2 = re + e;
        float sq_lik = sx2 - 2.f * xxmu + xmu2;
        float vz = s2 * s2;
        float sd2 = sdec * sdec;
        float vx = sd2 * sd2;
        wacc += 0.5f * (4096.f * LOG2PI + 4096.f * __logf(vx) + sq_lik / vx
                        + ra - 64.f * __logf(vz) - rb);
    }
    if (k == 0) red[wid] = wacc;
    __syncthreads();
    if (tid == 0) partial[blockIdx.x] = red[0] + red[1] + red[2] + red[3];
}

__global__ __launch_bounds__(256) void final_reduce_kernel(const float* __restrict__ partial,
                                                           float* __restrict__ out) {
    __shared__ float red[4];
    int tid = threadIdx.x;
    float v = 0.f;
    for (int i = tid; i < 512; i += 256) v += partial[i];
#pragma unroll
    for (int d = 1; d < 64; d <<= 1) v += __shfl_xor(v, d);
    if ((tid & 63) == 0) red[tid >> 6] = v;
    __syncthreads();
    if (tid == 0) out[0] = red[0] + red[1] + red[2] + red[3];
}

extern "C" void kernel_launch(void* const* d_in, const int* in_sizes, int n_in,
                              void* d_out, int out_size, void* d_ws, size_t ws_size,
                              hipStream_t stream) {
    const float* x     = (const float*)d_in[0];
    const float* noise = (const float*)d_in[1];
    const float* We    = (const float*)d_in[2];
    const float* bem   = (const float*)d_in[3];
    const float* Wes   = (const float*)d_in[4];
    const float* bes   = (const float*)d_in[5];
    const float* Wd    = (const float*)d_in[6];
    const float* bdm   = (const float*)d_in[7];
    const float* Wds   = (const float*)d_in[8];
    const float* bds   = (const float*)d_in[9];

    int ksplit = (ws_size >= 39340544ull) ? 4 : (ws_size >= 20466176ull ? 2 : 1);
    int steps = 128 / ksplit;         // BK=32 tiles per k-slice
    int kslice = steps * 32;
    int ppstride = ksplit * 144;

    char* ws = (char*)d_ws;
    size_t ppbytes = (size_t)16384 * ppstride * 4;
    float* Pp           = (float*)ws;
    unsigned char* Bp   = (unsigned char*)(ws + ppbytes);   // 1,179,648 B used
    float* G            = (float*)(ws + ppbytes + 1572864);
    float* hv           = (float*)(ws + ppbytes + 1572864 + 16384);
    float* ev           = (float*)(ws + ppbytes + 1572864 + 16640);
    float* partial      = (float*)(ws + ppbytes + 1572864 + 16896);

    prep_kernel<<<4289, 256, 0, stream>>>(We, Wes, Wd, bdm, Bp, G, hv, ev);
    gemm_kernel<<<dim3(128, ksplit), 256, 0, stream>>>(x, Bp, Pp, steps, kslice, ppstride);
    phase2_kernel<<<512, 256, 0, stream>>>(Pp, noise, bem, Wds, bes, bds, G, hv, ev,
                                           partial, ksplit, ppstride);
    final_reduce_kernel<<<1, 256, 0, stream>>>(partial, (float*)d_out);
}

// Round 13
// 98.258 us; speedup vs baseline: 1.2870x; 1.0326x over previous
//
#include <hip/hip_runtime.h>
#include <hip/hip_bf16.h>

#define LOG2PI 1.8378770664093453f

// N=16384, M(K-dim)=4096, K(latent)=64.
// GEMM: Out[n][c] = sum_m x[n][m] * Bcat[c][m], staged cols c in [0,144):
//   c 0-63: W_enc_mu col, 64-127: W_dec_mu row (c-64), 128: W_enc_sigma, 129: b_dec_mu.
// Split-K: KSPLIT slices of m; bf16 partials Pp16[row][ks][144] (stride ppstride,
// bf16 elems); fp32 sum(x^2) partials in SxP[row][4] (only [0,ksplit) used).
//
// Bp layout: per k-tile kt (32 m-values, 128 tiles), a 9216-B linear LDS image:
//   offset col*64 + u*16 holds Bcat[col][kt*32 + (u^q(col))*8 .. +8] as 8 bf16,
//   q(col) = (col + (col>>2)) & 3  (2-way-free ds_read banking). 144 cols.
// A LDS image per step: row*128 + u8*16 holds x[row][t*32 + (u8^(row&7))*4 ..+4] fp32.
// BM=128, BK=32, 4 waves (2m x 2n asym: 5/4 frags).
// TRIPLE-buffered, depth-2 prefetch (vmcnt(14)), 2 blocks/CU, k-phase stagger.

typedef __attribute__((ext_vector_type(8))) short bf16x8;
typedef __attribute__((ext_vector_type(4))) float f32x4;

__device__ __forceinline__ unsigned short f2bf(float f) {
    unsigned int u = __builtin_bit_cast(unsigned int, f);
    u += 0x7FFFu + ((u >> 16) & 1u);
    return (unsigned short)(u >> 16);
}
__device__ __forceinline__ float bf2f(unsigned short u) {
    unsigned int x = ((unsigned int)u) << 16;
    return __builtin_bit_cast(float, x);
}
__device__ __forceinline__ short f2bf_s(float f) {
    return (short)__builtin_bit_cast(unsigned short, __float2bfloat16(f));
}
__device__ __forceinline__ void gll16(const void* g, void* l) {
    __builtin_amdgcn_global_load_lds(
        (const __attribute__((address_space(1))) void*)g,
        (__attribute__((address_space(3))) void*)l, 16, 0, 0);
}

// ---------------- merged prep: blocks 0-127 pack B; blocks 128+ compute G/h/e
__global__ __launch_bounds__(256) void prep_kernel(const float* __restrict__ We,
        const float* __restrict__ Wes, const float* __restrict__ Wd,
        const float* __restrict__ bd, unsigned char* __restrict__ Bp,
        float* __restrict__ G, float* __restrict__ hv, float* __restrict__ ev) {
    __shared__ float WeL[2048];   // [32 m][64 c]
    __shared__ float WdL[2048];   // [64 r][32 m]
    __shared__ float WesL[32], bdL[32];
    __shared__ float red[256];
    const int t = threadIdx.x;
    if (blockIdx.x < 128) {
        const int kt = blockIdx.x;    // [0,128)
#pragma unroll
        for (int i = 0; i < 2; ++i) {
            int q = t + 256 * i;
            *reinterpret_cast<f32x4*>(WeL + q * 4) =
                *reinterpret_cast<const f32x4*>(We + (size_t)kt * 2048 + q * 4);
        }
#pragma unroll
        for (int i = 0; i < 2; ++i) {
            int f = t + 256 * i;
            int r = f >> 3, s4 = f & 7;
            *reinterpret_cast<f32x4*>(WdL + r * 32 + s4 * 4) =
                *reinterpret_cast<const f32x4*>(Wd + (size_t)r * 4096 + kt * 32 + s4 * 4);
        }
        if (t < 8) {
            *reinterpret_cast<f32x4*>(WesL + t * 4) =
                *reinterpret_cast<const f32x4*>(Wes + kt * 32 + t * 4);
        } else if (t < 16) {
            int q = t - 8;
            *reinterpret_cast<f32x4*>(bdL + q * 4) =
                *reinterpret_cast<const f32x4*>(bd + kt * 32 + q * 4);
        }
        __syncthreads();
#pragma unroll
        for (int i = 0; i < 3; ++i) {
            int cidx = t + 256 * i;            // [0,576) = col*4 + u
            if (cidx < 576) {
                int col = cidx >> 2, u = cidx & 3;
                int ku = u ^ ((col + (col >> 2)) & 3);
                unsigned short out[8];
#pragma unroll
                for (int j = 0; j < 8; ++j) {
                    int ml = ku * 8 + j;
                    float v = 0.f;
                    if (col < 64)        v = WeL[ml * 64 + col];
                    else if (col < 128)  v = WdL[(col - 64) * 32 + ml];
                    else if (col == 128) v = WesL[ml];
                    else if (col == 129) v = bdL[ml];
                    out[j] = f2bf(v);
                }
                *reinterpret_cast<uint4*>(Bp + ((size_t)kt * 576 + cidx) * 16) =
                    *reinterpret_cast<uint4*>(out);
            }
        }
        return;
    }
    // ---- G / h / e part
    const int b = blockIdx.x - 128;
    float p = 0.f;
    if (b < 4096) {
        int a = b >> 6, c = b & 63;
        const f32x4* ra = reinterpret_cast<const f32x4*>(Wd + (size_t)a * 4096);
        const f32x4* rc = reinterpret_cast<const f32x4*>(Wd + (size_t)c * 4096);
        for (int j = t; j < 1024; j += 256) {
            f32x4 u = ra[j], v = rc[j];
            p += u[0] * v[0] + u[1] * v[1] + u[2] * v[2] + u[3] * v[3];
        }
    } else if (b < 4160) {
        int a = b - 4096;
        const f32x4* ra = reinterpret_cast<const f32x4*>(Wd + (size_t)a * 4096);
        const f32x4* rb = reinterpret_cast<const f32x4*>(bd);
        for (int j = t; j < 1024; j += 256) {
            f32x4 u = ra[j], v = rb[j];
            p += u[0] * v[0] + u[1] * v[1] + u[2] * v[2] + u[3] * v[3];
        }
    } else {
        const f32x4* rb = reinterpret_cast<const f32x4*>(bd);
        for (int j = t; j < 1024; j += 256) {
            f32x4 v = rb[j];
            p += v[0] * v[0] + v[1] * v[1] + v[2] * v[2] + v[3] * v[3];
        }
    }
    red[t] = p;
    __syncthreads();
    for (int s = 128; s > 0; s >>= 1) { if (t < s) red[t] += red[t + s]; __syncthreads(); }
    if (t == 0) {
        if (b < 4096) G[b] = red[0];
        else if (b < 4160) hv[b - 4096] = red[0];
        else ev[0] = red[0];
    }
}

// ---------------- main GEMM: BM=128, BK=32, triple-buffer depth-2, bf16 partials
__global__ __launch_bounds__(256, 2) void gemm_kernel(const float* __restrict__ x,
        const unsigned char* __restrict__ Bp, unsigned short* __restrict__ Pp16,
        float* __restrict__ SxP, int steps, int kslice, int ppstride) {
    __shared__ __align__(16) char lds[76800];    // 3 bufs x (A 16384 + B 9216)
    const int tid = threadIdx.x;
    const int lane = tid & 63, w = tid >> 6;
    const int wm = w >> 1, wn = w & 1;           // 2m x 2n; wn0: cols 0-79, wn1: 80-143
    const int l15 = lane & 15, kg = lane >> 4;
    const int rowbase = blockIdx.x * 128;
    const int ks = blockIdx.y;

    // A staging: 4 instrs/thread; instr i -> linear chunk q = i*256+tid
    const float* xA[4];
#pragma unroll
    for (int i = 0; i < 4; ++i) {
        int q = i * 256 + tid;
        int row = q >> 3, u8 = q & 7;
        int co = (u8 ^ (row & 7)) << 2;
        xA[i] = x + (size_t)(rowbase + row) * 4096 + (size_t)ks * kslice + co;
    }

    f32x4 acc[4][5];
#pragma unroll
    for (int mi = 0; mi < 4; ++mi)
#pragma unroll
        for (int ni = 0; ni < 5; ++ni) acc[mi][ni] = (f32x4){0.f, 0.f, 0.f, 0.f};
    float sxa[4] = {0.f, 0.f, 0.f, 0.f};

#define STAGE(buf, tt) do { \
        char* Lb_ = lds + (buf) * 25600; \
        const size_t tb_ = (size_t)(ks * steps + (tt)) * 9216; \
        _Pragma("unroll") \
        for (int i_ = 0; i_ < 4; ++i_) \
            gll16(xA[i_] + (tt) * 32, Lb_ + i_ * 4096 + tid * 16); \
        _Pragma("unroll") \
        for (int j_ = 0; j_ < 2; ++j_) \
            gll16(Bp + tb_ + (size_t)(j_ * 256 + tid) * 16, \
                  Lb_ + 16384 + (j_ * 256 + tid) * 16); \
        if (kg == 0) \
            gll16(Bp + tb_ + (size_t)(512 + w * 16 + l15) * 16, \
                  Lb_ + 16384 + (512 + w * 16 + l15) * 16); \
    } while (0)

#define COMPUTE(buf) do { \
        char* A0 = lds + (buf) * 25600; \
        char* B0 = A0 + 16384; \
        bf16x8 bfr[5]; \
        _Pragma("unroll") \
        for (int ni_ = 0; ni_ < 5; ++ni_) { \
            if (wn == 0 || ni_ < 4) { \
                int col_ = wn * 80 + ni_ * 16 + l15; \
                int q_ = (col_ + (col_ >> 2)) & 3; \
                bfr[ni_] = *reinterpret_cast<const bf16x8*>( \
                    B0 + col_ * 64 + ((kg ^ q_) << 4)); \
            } \
        } \
        _Pragma("unroll") \
        for (int mi_ = 0; mi_ < 4; ++mi_) { \
            int row_ = wm * 64 + mi_ * 16 + l15; \
            int e0_ = (kg << 1) ^ (row_ & 7); \
            f32x4 fa_ = *reinterpret_cast<const f32x4*>(A0 + row_ * 128 + (e0_ << 4)); \
            f32x4 fb_ = *reinterpret_cast<const f32x4*>(A0 + row_ * 128 + ((e0_ ^ 1) << 4)); \
            bf16x8 af_; \
            af_[0] = f2bf_s(fa_[0]); af_[1] = f2bf_s(fa_[1]); \
            af_[2] = f2bf_s(fa_[2]); af_[3] = f2bf_s(fa_[3]); \
            af_[4] = f2bf_s(fb_[0]); af_[5] = f2bf_s(fb_[1]); \
            af_[6] = f2bf_s(fb_[2]); af_[7] = f2bf_s(fb_[3]); \
            if (wn == 0) { \
                sxa[mi_] += fa_[0]*fa_[0] + fa_[1]*fa_[1] + fa_[2]*fa_[2] + fa_[3]*fa_[3] \
                          + fb_[0]*fb_[0] + fb_[1]*fb_[1] + fb_[2]*fb_[2] + fb_[3]*fb_[3]; \
            } \
            _Pragma("unroll") \
            for (int ni_ = 0; ni_ < 5; ++ni_) { \
                if (wn == 0 || ni_ < 4) \
                    acc[mi_][ni_] = __builtin_amdgcn_mfma_f32_16x16x32_bf16( \
                        af_, bfr[ni_], acc[mi_][ni_], 0, 0, 0); \
            } \
        } \
    } while (0)

    // channel-de-aliasing stagger: rotate k-tile order per block
    const int phase = (blockIdx.x + ks * 8) & (steps - 1);
    int tp0 = phase;
    int tpn = (tp0 + 1 == steps) ? 0 : tp0 + 1;
    STAGE(0, tp0);
    STAGE(1, tpn);
    int cur = 0;
    for (int t = 0; t < steps; ++t) {
        if (t + 2 < steps) {
            tpn = (tpn + 1 == steps) ? 0 : tpn + 1;
            int b2 = (cur == 0) ? 2 : cur - 1;        // (cur+2)%3
            STAGE(b2, tpn);
            asm volatile("s_waitcnt vmcnt(14)" ::: "memory");  // step-t loads done
        } else if (t + 2 == steps) {
            asm volatile("s_waitcnt vmcnt(7)" ::: "memory");
        } else {
            asm volatile("s_waitcnt vmcnt(0)" ::: "memory");
        }
        __builtin_amdgcn_s_barrier();
        asm volatile("" ::: "memory");
        COMPUTE(cur);
        asm volatile("" ::: "memory");
        __builtin_amdgcn_s_barrier();
        cur = (cur == 2) ? 0 : cur + 1;
    }
#undef STAGE
#undef COMPUTE

    // reduce sx2 across kg groups (lanes 0-15 end with full row sums)
#pragma unroll
    for (int mi = 0; mi < 4; ++mi) {
        sxa[mi] += __shfl_xor(sxa[mi], 16);
        sxa[mi] += __shfl_xor(sxa[mi], 32);
    }
    // fp32 sum(x^2) partials to side array
    if (wn == 0 && lane < 16) {
#pragma unroll
        for (int mi = 0; mi < 4; ++mi)
            SxP[(size_t)(rowbase + wm * 64 + mi * 16 + lane) * 4 + ks] = sxa[mi];
    }

    // ---- coalesced bf16 writeback in two 64-row passes via LDS C-tile [64][148]
    float* C = reinterpret_cast<float*>(lds);
#pragma unroll
    for (int pass = 0; pass < 2; ++pass) {
        __syncthreads();
        if (wm == pass) {
#pragma unroll
            for (int mi = 0; mi < 4; ++mi)
#pragma unroll
                for (int ni = 0; ni < 5; ++ni) {
                    if (wn == 0 || ni < 4) {
                        int col = wn * 80 + ni * 16 + l15;
#pragma unroll
                        for (int i2 = 0; i2 < 4; ++i2)
                            C[(mi * 16 + kg * 4 + i2) * 148 + col] = acc[mi][ni][i2];
                    }
                }
        }
        __syncthreads();
        // 64 rows x 18 chunks (8 bf16 = 16 B each) = 1152 stores
#pragma unroll
        for (int i = 0; i < 5; ++i) {
            int idx = tid + 256 * i;
            if (idx < 1152) {
                int r = idx / 18, c8 = idx % 18;
                const float* src = C + r * 148 + c8 * 8;
                unsigned short o[8];
#pragma unroll
                for (int j = 0; j < 8; ++j) o[j] = f2bf(src[j]);
                *reinterpret_cast<uint4*>(
                    Pp16 + (size_t)(rowbase + pass * 64 + r) * ppstride
                         + ks * 144 + c8 * 8) = *reinterpret_cast<uint4*>(o);
            }
        }
    }
}

// ---------------- phase 2: bf16 partials in, plain [64][64] G matvec
__global__ __launch_bounds__(256) void phase2_kernel(const unsigned short* __restrict__ Pp16,
        const float* __restrict__ SxP, const float* __restrict__ noise,
        const float* __restrict__ bem, const float* __restrict__ Wds,
        const float* __restrict__ bes_p, const float* __restrict__ bds_p,
        const float* __restrict__ G, const float* __restrict__ hv,
        const float* __restrict__ ev, float* __restrict__ partial,
        int ksplit, int ppstride) {
    __shared__ float Gl[4096];
    __shared__ float hl[64], wl[64], beml[64];
    __shared__ float zs[4][64];
    __shared__ float red[4];
    int tid = threadIdx.x;
    for (int i = tid; i < 4096; i += 256) Gl[i] = G[i];
    if (tid < 64) { hl[tid] = hv[tid]; wl[tid] = Wds[tid]; beml[tid] = bem[tid]; }
    __syncthreads();
    float bes = bes_p[0], bds = bds_p[0], e = ev[0];
    int wid = tid >> 6, k = tid & 63;
    const int sw = (k & 15) << 2;
    float wacc = 0.f;
#pragma unroll
    for (int rr = 0; rr < 8; ++rr) {
        int row = blockIdx.x * 32 + wid * 8 + rr;
        const unsigned short* base = Pp16 + (size_t)row * ppstride;
        float zmu = beml[k], ck = 0.f, se = bes, dd = 0.f, sx2 = 0.f;
        for (int s = 0; s < ksplit; ++s) {
            const unsigned short* b2 = base + s * 144;
            zmu += bf2f(b2[k]); ck += bf2f(b2[64 + k]);
            se += bf2f(b2[128]); dd += bf2f(b2[129]);
            sx2 += SxP[(size_t)row * 4 + s];
        }
        float nz = noise[(size_t)row * 64 + k];
        float s2 = se * se;
        float z = fmaf(s2, nz, zmu);
        zs[wid][k] = z;
        float t0 = 0.f, t1 = 0.f, t2 = 0.f, t3 = 0.f;
        const float* gr = &Gl[k * 64];
        const float* zr = &zs[wid][0];
#pragma unroll
        for (int jb = 0; jb < 16; ++jb) {
            int p = (jb * 4) ^ sw;
            f32x4 gv = *reinterpret_cast<const f32x4*>(gr + p);
            f32x4 zv = *reinterpret_cast<const f32x4*>(zr + p);
            t0 = fmaf(gv[0], zv[0], t0); t1 = fmaf(gv[1], zv[1], t1);
            t2 = fmaf(gv[2], zv[2], t2); t3 = fmaf(gv[3], zv[3], t3);
        }
        float t = (t0 + t1) + (t2 + t3);
        float ra = z * z;
        float rb = nz * nz;
        float rc = z * wl[k];
        float rd = z * ck;
        float re = z * fmaf(2.f, hl[k], t);
#pragma unroll
        for (int d = 1; d < 64; d <<= 1) {
            ra += __shfl_xor(ra, d); rb += __shfl_xor(rb, d);
            rc += __shfl_xor(rc, d); rd += __shfl_xor(rd, d);
            re += __shfl_xor(re, d);
        }
        float sdec = rc + bds;
        float xxmu = rd + dd;
        float xmu2 = re + e;
        float sq_lik = sx2 - 2.f * xxmu + xmu2;
        float vz = s2 * s2;
        float sd2 = sdec * sdec;
        float vx = sd2 * sd2;
        wacc += 0.5f * (4096.f * LOG2PI + 4096.f * __logf(vx) + sq_lik / vx
                        + ra - 64.f * __logf(vz) - rb);
    }
    if (k == 0) red[wid] = wacc;
    __syncthreads();
    if (tid == 0) partial[blockIdx.x] = red[0] + red[1] + red[2] + red[3];
}

__global__ __launch_bounds__(256) void final_reduce_kernel(const float* __restrict__ partial,
                                                           float* __restrict__ out) {
    __shared__ float red[4];
    int tid = threadIdx.x;
    float v = 0.f;
    for (int i = tid; i < 512; i += 256) v += partial[i];
#pragma unroll
    for (int d = 1; d < 64; d <<= 1) v += __shfl_xor(v, d);
    if ((tid & 63) == 0) red[tid >> 6] = v;
    __syncthreads();
    if (tid == 0) out[0] = red[0] + red[1] + red[2] + red[3];
}

extern "C" void kernel_launch(void* const* d_in, const int* in_sizes, int n_in,
                              void* d_out, int out_size, void* d_ws, size_t ws_size,
                              hipStream_t stream) {
    const float* x     = (const float*)d_in[0];
    const float* noise = (const float*)d_in[1];
    const float* We    = (const float*)d_in[2];
    const float* bem   = (const float*)d_in[3];
    const float* Wes   = (const float*)d_in[4];
    const float* bes   = (const float*)d_in[5];
    const float* Wd    = (const float*)d_in[6];
    const float* bdm   = (const float*)d_in[7];
    const float* Wds   = (const float*)d_in[8];
    const float* bds   = (const float*)d_in[9];

    int ksplit = (ws_size >= 22000000ull) ? 4 : (ws_size >= 12000000ull ? 2 : 1);
    int steps = 128 / ksplit;         // BK=32 tiles per k-slice
    int kslice = steps * 32;
    int ppstride = ksplit * 144;      // bf16 elements per row

    char* ws = (char*)d_ws;
    size_t ppbytes = (size_t)16384 * ppstride * 2;   // bf16 partials
    unsigned short* Pp16 = (unsigned short*)ws;
    unsigned char* Bp    = (unsigned char*)(ws + ppbytes);        // 1,179,648 B
    float* G             = (float*)(ws + ppbytes + 1572864);
    float* hv            = (float*)(ws + ppbytes + 1572864 + 16384);
    float* ev            = (float*)(ws + ppbytes + 1572864 + 16640);
    float* partial       = (float*)(ws + ppbytes + 1572864 + 16896);
    float* SxP           = (float*)(ws + ppbytes + 1572864 + 19456);  // 262,144 B

    prep_kernel<<<4289, 256, 0, stream>>>(We, Wes, Wd, bdm, Bp, G, hv, ev);
    gemm_kernel<<<dim3(128, ksplit), 256, 0, stream>>>(x, Bp, Pp16, SxP,
                                                       steps, kslice, ppstride);
    phase2_kernel<<<512, 256, 0, stream>>>(Pp16, SxP, noise, bem, Wds, bes, bds,
                                           G, hv, ev, partial, ksplit, ppstride);
    final_reduce_kernel<<<1, 256, 0, stream>>>(partial, (float*)d_out);
}